// Round 3
// baseline (189.453 us; speedup 1.0000x reference)
//
#include <hip/hip_runtime.h>
#include <math.h>

#define KHALF 5
#define MAXF 256  // max fire count per batch (Lp1 <= 128 here)

// K0 v7 "prep": fused weff + aws zero-background.
// Blocks [0, WB): w_eff/b_eff (one wave per output element, as before).
// Blocks [WB, WB+NFILL): grid-stride float4 zero of aws (17 MB at full-machine
// BW ~3us; lets k_awfired write only the <=2 nonzero entries per column).
__global__ void k_prep(const float* __restrict__ conv_w, const float* __restrict__ conv_b,
                       const float* __restrict__ proj_w, const float* __restrict__ proj_b,
                       float* __restrict__ w_eff, float* __restrict__ b_eff,
                       int KD, int C,
                       float* __restrict__ aws, long long awsN, int WB, int NFILL) {
    if ((int)blockIdx.x >= WB) {
        long long N4 = awsN >> 2;
        long long gid = (long long)(blockIdx.x - WB) * 256 + threadIdx.x;
        float4 z = make_float4(0.f, 0.f, 0.f, 0.f);
        float4* a4 = reinterpret_cast<float4*>(aws);
        long long stride = (long long)NFILL * 256;
        for (long long i = gid; i < N4; i += stride) a4[i] = z;
        int tail = (int)(awsN & 3);
        if (gid < tail) aws[4 * N4 + gid] = 0.f;
        return;
    }
    int gid = blockIdx.x * blockDim.x + threadIdx.x;
    int wave = gid >> 6;
    int lane = gid & 63;
    if (wave > KD) return;
    float s = 0.f;
    if (wave < KD) {
        const float* row = conv_w + (size_t)wave * C;
        for (int c = lane * 4; c < C; c += 256) {
            float4 v = *reinterpret_cast<const float4*>(row + c);
            float4 w = *reinterpret_cast<const float4*>(proj_w + c);
            s += v.x * w.x + v.y * w.y + v.z * w.z + v.w * w.w;
        }
    } else {
        for (int c = lane; c < C; c += 64) s += conv_b[c] * proj_w[c];
    }
#pragma unroll
    for (int off = 32; off > 0; off >>= 1) s += __shfl_down(s, off, 64);
    if (lane == 0) {
        if (wave < KD) w_eff[wave] = s;
        else           b_eff[0] = s + proj_b[0];
    }
}

// K2a v5: q[u][k] = dot(eouts[u,:], w_eff[k,:]), k=0..10. D==512 specialized.
// (unchanged — near its HBM floor)
__global__ __launch_bounds__(256) void k_qdot(const float* __restrict__ eouts,
                                              const float* __restrict__ w_eff,
                                              float* __restrict__ q, int BT) {
    __shared__ float tile[64 * 68];   // 17408 B
    __shared__ float wls[11 * 68];    //  2992 B
    __shared__ float part[64 * 89];   // 22784 B
    const int u0 = blockIdx.x * 64;
    const int rp = threadIdx.x & 31;
    const int s8 = threadIdx.x >> 5;
    float acc0[11], acc1[11];
#pragma unroll
    for (int k = 0; k < 11; ++k) { acc0[k] = 0.f; acc1[k] = 0.f; }
    for (int c = 0; c < 8; ++c) {
        __syncthreads();
#pragma unroll
        for (int it = 0; it < 4; ++it) {
            int idx = it * 256 + threadIdx.x;
            int r = idx >> 4, j4 = idx & 15;
            float4 v = *reinterpret_cast<const float4*>(
                eouts + (size_t)(u0 + r) * 512 + c * 64 + j4 * 4);
            *reinterpret_cast<float4*>(&tile[r * 68 + j4 * 4]) = v;
        }
        if (threadIdx.x < 176) {
            int k = threadIdx.x >> 4, sl = threadIdx.x & 15;
            float4 wv = *reinterpret_cast<const float4*>(
                w_eff + k * 512 + c * 64 + sl * 4);
            *reinterpret_cast<float4*>(&wls[k * 68 + sl * 4]) = wv;
        }
        __syncthreads();
#pragma unroll
        for (int j4 = 0; j4 < 2; ++j4) {
            const int dl = s8 * 8 + j4 * 4;
            float4 a0 = *reinterpret_cast<const float4*>(&tile[rp * 68 + dl]);
            float4 a1 = *reinterpret_cast<const float4*>(&tile[(rp + 32) * 68 + dl]);
#pragma unroll
            for (int k = 0; k < 11; ++k) {
                float4 wv = *reinterpret_cast<const float4*>(&wls[k * 68 + dl]);
                acc0[k] += a0.x * wv.x + a0.y * wv.y + a0.z * wv.z + a0.w * wv.w;
                acc1[k] += a1.x * wv.x + a1.y * wv.y + a1.z * wv.z + a1.w * wv.w;
            }
        }
    }
    __syncthreads();
#pragma unroll
    for (int k = 0; k < 11; ++k) {
        part[rp * 89 + s8 * 11 + k] = acc0[k];
        part[(rp + 32) * 89 + s8 * 11 + k] = acc1[k];
    }
    __syncthreads();
    if (threadIdx.x < 64) {
        int r = threadIdx.x;
        const float* p = &part[r * 89];
        float o[12];
#pragma unroll
        for (int k = 0; k < 11; ++k) {
            float s0 = (p[0 * 11 + k] + p[1 * 11 + k]) + (p[2 * 11 + k] + p[3 * 11 + k]);
            float s1 = (p[4 * 11 + k] + p[5 * 11 + k]) + (p[6 * 11 + k] + p[7 * 11 + k]);
            o[k] = s0 + s1;
        }
        o[11] = 0.f;
        float4* dst = reinterpret_cast<float4*>(q + (size_t)(u0 + r) * 12);
        dst[0] = make_float4(o[0], o[1], o[2], o[3]);
        dst[1] = make_float4(o[4], o[5], o[6], o[7]);
        dst[2] = make_float4(o[8], o[9], o[10], o[11]);
    }
}

// K2 fallback (generic D): windowed dot, one wave per (b,t), writes alpha.
__global__ void k_alpha(const float* __restrict__ eouts,
                        const float* __restrict__ w_eff,
                        const float* __restrict__ b_eff,
                        float* __restrict__ alpha,
                        int B, int T, int D) {
    const int W = 2 * KHALF + 1;
    int gid = blockIdx.x * blockDim.x + threadIdx.x;
    int wave = gid >> 6;
    int lane = gid & 63;
    if (wave >= B * T) return;
    int b = wave / T;
    int t = wave - b * T;
    int WD = W * D;
    int t0 = t - KHALF;
    float s = 0.f;
    if (t0 >= 0 && t0 + W <= T) {
        const float* base = eouts + ((size_t)b * T + t0) * D;
        for (int j = lane * 4; j < WD; j += 256) {
            float4 v = *reinterpret_cast<const float4*>(base + j);
            float4 w = *reinterpret_cast<const float4*>(w_eff + j);
            s += v.x * w.x + v.y * w.y + v.z * w.z + v.w * w.w;
        }
    } else {
        const float* base = eouts + (size_t)b * T * D;
        for (int j = lane; j < WD; j += 64) {
            int tt = t0 + j / D;
            if (tt >= 0 && tt < T) {
                int d = j - (j / D) * D;
                s += base[(size_t)tt * D + d] * w_eff[j];
            }
        }
    }
#pragma unroll
    for (int off = 32; off > 0; off >>= 1) s += __shfl_down(s, off, 64);
    if (lane == 0) {
        float logit = s + b_eff[0];
        alpha[(size_t)b * T + t] = 1.f / (1.f + expf(-logit));
    }
}

// K3 v7: fused sigmoid(q-window)+alpha-write+rowsum+normalize+fire scan.
// Fused path (fused==1, T%256==0): stages qbuf per 256-chunk into LDS with
// the SAME layout as old k_sigpart (qs[266*12]); per-chunk partial sums use
// the identical 4-wave shfl tree + ordered accumulation -> bit-identical
// ssum -> bit-identical fire positions vs v6. Saves one kernel launch and
// the alpha HBM round-trip before the scan.
__global__ void k_chain(const float* __restrict__ alpha_in,   // fallback only
                        const float* __restrict__ qbuf,       // fused only
                        const float* __restrict__ b_eff,      // fused only
                        int fused,
                        const int* __restrict__ elens,
                        const int* __restrict__ ylens,
                        float* __restrict__ alpha_out,        // fused only
                        float* __restrict__ anorm,
                        int* __restrict__ n_fired,
                        int* __restrict__ fire_t,
                        float* __restrict__ fire_a1,
                        float* __restrict__ fire_a2,
                        int T, int Lp1) {
    extern __shared__ float an[];   // [0,T): alpha->anorm; [T,2T): chunk prefix
    float* pf = an + T;
    __shared__ float qs[266 * 12];
    __shared__ float sm[64];
    __shared__ float stot;
    int b = blockIdx.x;
    if (fused) {
        const float* qb = qbuf + (size_t)b * T * 12;
        const int lim = T * 12;
        const int nchunks = T >> 8;
        const float be = b_eff[0];
        for (int c = 0; c < nchunks; ++c) {
            __syncthreads();  // WAR on qs from previous chunk
            int t0 = c * 256;
            int base = (t0 - 5) * 12;
            for (int i = threadIdx.x; i < 266 * 12; i += 256) {
                int gi = base + i;
                qs[i] = (gi >= 0 && gi < lim) ? qb[gi] : 0.f;
            }
            __syncthreads();
            int t = t0 + threadIdx.x;
            float sacc = be;
#pragma unroll
            for (int k = 0; k < 11; ++k) sacc += qs[(threadIdx.x + k) * 12 + k];
            float al = 1.f / (1.f + expf(-sacc));
            an[t] = al;
            alpha_out[(size_t)b * T + t] = al;
            float s = al;
            int lane = threadIdx.x & 63;
            int w = threadIdx.x >> 6;
#pragma unroll
            for (int off = 32; off > 0; off >>= 1) s += __shfl_down(s, off, 64);
            if (lane == 0) sm[c * 4 + w] = s;
        }
        __syncthreads();
        if (threadIdx.x == 0) {
            float tot = 0.f;
            for (int c = 0; c < nchunks; ++c) {
                float pc = sm[c * 4];
                pc += sm[c * 4 + 1];
                pc += sm[c * 4 + 2];
                pc += sm[c * 4 + 3];
                tot += pc;
            }
            stot = tot;
        }
    } else {
        const float* row = alpha_in + (size_t)b * T;
        for (int i = threadIdx.x; i < T; i += blockDim.x) an[i] = row[i];
        __syncthreads();
        float s = 0.f;
        for (int i = threadIdx.x; i < T; i += blockDim.x) s += an[i];
        int lane0 = threadIdx.x & 63;
        int w0 = threadIdx.x >> 6;
#pragma unroll
        for (int off = 32; off > 0; off >>= 1) s += __shfl_down(s, off, 64);
        if (lane0 == 0) sm[w0] = s;
        __syncthreads();
        if (threadIdx.x == 0) {
            float tot = 0.f;
            int nw = blockDim.x >> 6;
            for (int i = 0; i < nw; ++i) tot += sm[i];
            stot = tot;
        }
    }
    __syncthreads();
    float ssum = stot;
    float yl = (float)ylens[b];
    float* __restrict__ anb = anorm + (size_t)b * T;
    for (int i = threadIdx.x; i < T; i += blockDim.x) {
        float v = an[i] / ssum * yl;
        an[i] = v;
        anb[i] = v;
    }
    __syncthreads();
    // per-64-chunk inclusive prefix (same tree order as before)
    {
        int wv = threadIdx.x >> 6, ln = threadIdx.x & 63;
        int nchunks = (T + 63) >> 6;
        for (int c = wv; c < nchunks; c += 4) {
            int t = c * 64 + ln;
            float P = (t < T) ? an[t] : 0.f;
#pragma unroll
            for (int off = 1; off < 64; off <<= 1) {
                float tmp = __shfl_up(P, off, 64);
                if (ln >= off) P += tmp;
            }
            if (t < T) pf[t] = P;
        }
    }
    __syncthreads();
    if (threadIdx.x >= 64) return;
    int lane = threadIdx.x;
    int elen = elens[b];
    if (elen > T) elen = T;
    const int ylen = ylens[b];
    int* __restrict__ ft = fire_t + (size_t)b * Lp1;
    float* __restrict__ fa1 = fire_a1 + (size_t)b * Lp1;
    float* __restrict__ fa2 = fire_a2 + (size_t)b * Lp1;
    float accum = 0.f;
    int n = 0;
    bool done = false;
    for (int t0 = 0; t0 < elen && !done; t0 += 64) {
        int nv = elen - t0;
        if (nv > 64) nv = 64;
        float P = (t0 + lane < T) ? pf[t0 + lane] : 0.f;
        unsigned long long validmask = (nv == 64) ? ~0ull : ((1ull << nv) - 1ull);
        float base = accum;
        int start = 0;
        while (true) {
            bool cond = (base + P >= 0.9f);
            unsigned long long bal = __ballot(cond) & validmask;
            if (start > 0) bal &= (~0ull) << start;
            if (bal == 0) break;
            int u = __builtin_ctzll(bal);
            float Pu = pf[t0 + u];   // broadcast LDS read
            float au = an[t0 + u];   // broadcast LDS read
            float accum_f = base + Pu;
            float ak1 = 1.f - accum_f;
            float ak2 = au - ak1;
            if (lane == 0) { ft[n] = t0 + u; fa1[n] = ak1; fa2[n] = ak2; }
            ++n;
            if (n >= ylen) { done = true; break; }
            base = ak2 - Pu;
            start = u + 1;
            if (start >= nv) break;
        }
        if (!done) accum = base + pf[t0 + nv - 1];
    }
    if (lane == 0) n_fired[b] = n;
}

// K4 v7: aws sparse writer (background pre-zeroed by k_prep) + fired.
// aws part: <=2 stores per (b,t) column instead of Lp1 column-sweep stores.
// fired part: one half-block (128 lanes) per (b,n), float4 over d (identical
// per-component arithmetic to v6's scalar per-d loop), 4-deep t-unroll ->
// 16B/lane loads with 4 in flight; n>=nf rows write float4 zeros.
__global__ void k_awfired(const float* __restrict__ eouts,
                          const float* __restrict__ anorm,
                          const int* __restrict__ elens,
                          const int* __restrict__ ylens,
                          const int* __restrict__ n_fired,
                          const int* __restrict__ fire_t,
                          const float* __restrict__ fire_a1,
                          const float* __restrict__ fire_a2,
                          float* __restrict__ aws,
                          float* __restrict__ fired,
                          int T, int D, int L, int Lp1,
                          int AB, int tcpb, int nLh) {
    if ((int)blockIdx.x < AB) {
        __shared__ int fts[MAXF];
        __shared__ float a1s[MAXF];
        __shared__ float a2s[MAXF];
        int b = blockIdx.x / tcpb;
        int tc = blockIdx.x % tcpb;
        int nf = n_fired[b];
        for (int i = threadIdx.x; i < nf; i += blockDim.x) {
            fts[i] = fire_t[(size_t)b * Lp1 + i];
            a1s[i] = fire_a1[(size_t)b * Lp1 + i];
            a2s[i] = fire_a2[(size_t)b * Lp1 + i];
        }
        __syncthreads();
        int t = tc * 256 + threadIdx.x;
        if (t >= T) return;
        int elen = elens[b];
        if (elen > T) elen = T;
        int ylen = ylens[b];
        if (t >= elen) return;                 // background zero (pre-zeroed)
        int lo = 0, hi = nf;
        while (lo < hi) {
            int mid = (lo + hi) >> 1;
            if (fts[mid] < t) lo = mid + 1; else hi = mid;
        }
        int rowi = lo;
        bool isfire = (rowi < nf && fts[rowi] == t);
        float* col = aws + (size_t)b * Lp1 * T + t;
        if (isfire) {
            col[(size_t)rowi * T] = a1s[rowi];
            col[(size_t)(rowi + 1) * T] = a2s[rowi];
        } else if (rowi < ylen) {
            col[(size_t)rowi * T] = anorm[(size_t)b * T + t];
        }
    } else {
        int idx = blockIdx.x - AB;
        int b = idx / nLh;
        int j = idx % nLh;
        int half = threadIdx.x >> 7;
        int dl = threadIdx.x & 127;
        int n = 2 * j + half;
        if (n >= L) return;
        int nf = n_fired[b];
        if ((D & 3) == 0) {
            int D4 = D >> 2;
            float4* dst = reinterpret_cast<float4*>(fired + ((size_t)b * L + n) * D);
            if (n >= nf) {
                for (int d4 = dl; d4 < D4; d4 += 128)
                    dst[d4] = make_float4(0.f, 0.f, 0.f, 0.f);
                return;
            }
            int t0 = (n == 0) ? 0 : fire_t[(size_t)b * Lp1 + n - 1];
            int t1 = fire_t[(size_t)b * Lp1 + n];
            float ak1 = fire_a1[(size_t)b * Lp1 + n];
            float ak2p = (n > 0) ? fire_a2[(size_t)b * Lp1 + n - 1] : 0.f;
            const float* an_g = anorm + (size_t)b * T;
            const float4* ebase = reinterpret_cast<const float4*>(
                eouts + ((size_t)b * T + t0) * D);
            for (int d4 = dl; d4 < D4; d4 += 128) {
                const float4* e = ebase + d4;
                float4 accv;
                if (t1 == t0) {
                    float4 v = e[0];
                    accv.x = ak1 * v.x; accv.y = ak1 * v.y;
                    accv.z = ak1 * v.z; accv.w = ak1 * v.w;
                } else {
                    float w0 = (n > 0) ? ak2p : an_g[t0];
                    float4 v = e[0];
                    accv.x = w0 * v.x; accv.y = w0 * v.y;
                    accv.z = w0 * v.z; accv.w = w0 * v.w;
                    float4 a0 = make_float4(0.f, 0.f, 0.f, 0.f);
                    float4 a1 = a0, a2 = a0, a3 = a0;
                    int t = t0 + 1;
                    const float4* ee = e + D4;
                    for (; t + 3 < t1; t += 4, ee += 4 * (size_t)D4) {
                        float wa = an_g[t], wb = an_g[t + 1];
                        float wc = an_g[t + 2], wd = an_g[t + 3];
                        float4 va = ee[0], vb = ee[D4], vc = ee[2 * (size_t)D4], vd = ee[3 * (size_t)D4];
                        a0.x += wa * va.x; a0.y += wa * va.y; a0.z += wa * va.z; a0.w += wa * va.w;
                        a1.x += wb * vb.x; a1.y += wb * vb.y; a1.z += wb * vb.z; a1.w += wb * vb.w;
                        a2.x += wc * vc.x; a2.y += wc * vc.y; a2.z += wc * vc.z; a2.w += wc * vc.w;
                        a3.x += wd * vd.x; a3.y += wd * vd.y; a3.z += wd * vd.z; a3.w += wd * vd.w;
                    }
                    for (; t < t1; ++t, ee += D4) {
                        float wa = an_g[t];
                        float4 va = ee[0];
                        a0.x += wa * va.x; a0.y += wa * va.y; a0.z += wa * va.z; a0.w += wa * va.w;
                    }
                    accv.x += ((a0.x + a1.x) + (a2.x + a3.x));
                    accv.y += ((a0.y + a1.y) + (a2.y + a3.y));
                    accv.z += ((a0.z + a1.z) + (a2.z + a3.z));
                    accv.w += ((a0.w + a1.w) + (a2.w + a3.w));
                    float4 vl = ee[0];   // row t1
                    accv.x += ak1 * vl.x; accv.y += ak1 * vl.y;
                    accv.z += ak1 * vl.z; accv.w += ak1 * vl.w;
                }
                dst[d4] = accv;
            }
        } else {
            float* dst = fired + ((size_t)b * L + n) * D;
            if (n >= nf) {
                for (int d = dl; d < D; d += 128) dst[d] = 0.f;
                return;
            }
            int t0 = (n == 0) ? 0 : fire_t[(size_t)b * Lp1 + n - 1];
            int t1 = fire_t[(size_t)b * Lp1 + n];
            float ak1 = fire_a1[(size_t)b * Lp1 + n];
            float ak2p = (n > 0) ? fire_a2[(size_t)b * Lp1 + n - 1] : 0.f;
            const float* an_g = anorm + (size_t)b * T;
            for (int d = dl; d < D; d += 128) {
                const float* e = eouts + ((size_t)b * T + t0) * D + d;
                float accv;
                if (t1 == t0) {
                    accv = ak1 * e[0];
                } else {
                    float w0 = (n > 0) ? ak2p : an_g[t0];
                    accv = w0 * e[0];
                    float a0 = 0.f, a1 = 0.f, a2 = 0.f, a3 = 0.f;
                    int t = t0 + 1;
                    const float* ee = e + D;
                    for (; t + 3 < t1; t += 4, ee += 4 * (size_t)D) {
                        a0 += an_g[t]     * ee[0];
                        a1 += an_g[t + 1] * ee[D];
                        a2 += an_g[t + 2] * ee[2 * (size_t)D];
                        a3 += an_g[t + 3] * ee[3 * (size_t)D];
                    }
                    for (; t < t1; ++t, ee += D) a0 += an_g[t] * ee[0];
                    accv += ((a0 + a1) + (a2 + a3));
                    accv += ak1 * ee[0];
                }
                dst[d] = accv;
            }
        }
    }
}

extern "C" void kernel_launch(void* const* d_in, const int* in_sizes, int n_in,
                              void* d_out, int out_size, void* d_ws, size_t ws_size,
                              hipStream_t stream) {
    const float* eouts  = (const float*)d_in[0];
    const float* conv_w = (const float*)d_in[1];
    const float* conv_b = (const float*)d_in[2];
    const float* proj_w = (const float*)d_in[3];
    const float* proj_b = (const float*)d_in[4];
    const int*   elens  = (const int*)d_in[5];
    const int*   ylens  = (const int*)d_in[6];

    const int B = in_sizes[5];
    const int C = in_sizes[2];
    const int W = 2 * KHALF + 1;
    const int D = in_sizes[1] / (W * C);
    const int T = in_sizes[0] / (B * D);
    const int L = (out_size - 2 * B * T) / (B * (D + T));
    const int Lp1 = L + 1;
    const int BT = B * T;

    float* out   = (float*)d_out;
    float* fired = out;                      // [B, L, D]
    float* alpha = out + (size_t)B * L * D;  // [B, T]
    float* aws   = alpha + (size_t)B * T;    // [B, 1, Lp1, T]

    char*  ws        = (char*)d_ws;
    float* w_eff     = (float*)ws;                              // W*D floats
    float* b_eff     = (float*)(ws + (size_t)W * D * 4);        // 1 float (+pad)
    int*   n_fired   = (int*)(b_eff + 16);                      // B ints
    int*   fire_t    = n_fired + B + 16;                        // B*Lp1 ints
    float* fire_a1   = (float*)(fire_t + (size_t)B * Lp1 + 16); // B*Lp1 floats
    float* fire_a2   = fire_a1 + (size_t)B * Lp1 + 16;          // B*Lp1 floats
    float* anorm     = fire_a2 + (size_t)B * Lp1 + 16;          // B*T floats
    float* qbuf      = anorm + (size_t)B * T + 16;              // BT*12 floats
    size_t ws_need   = (size_t)((char*)(qbuf + (size_t)BT * 12 + 16) - ws);

    const int KD = W * D;
    {
        long long wthreads = (long long)(KD + 1) * 64;
        int WB = (int)((wthreads + 255) / 256);
        int NFILL = 2048;
        long long awsN = (long long)B * Lp1 * T;
        k_prep<<<WB + NFILL, 256, 0, stream>>>(conv_w, conv_b, proj_w, proj_b,
                                               w_eff, b_eff, KD, C,
                                               aws, awsN, WB, NFILL);
    }

    const bool fast = (ws_size >= ws_need) && (D == 512) && (C == 512) &&
                      (BT % 64 == 0) && (T % 256 == 0) && (T <= 16384) &&
                      (Lp1 <= MAXF);
    if (fast) {
        k_qdot<<<BT / 64, 256, 0, stream>>>(eouts, w_eff, qbuf, BT);
        // fused sigmoid+scan; alpha written by k_chain directly
        k_chain<<<B, 256, 2 * T * sizeof(float), stream>>>(
            nullptr, qbuf, b_eff, 1,
            elens, ylens, alpha, anorm,
            n_fired, fire_t, fire_a1, fire_a2, T, Lp1);
    } else {
        long long threads = (long long)BT * 64;
        int blocks = (int)((threads + 255) / 256);
        k_alpha<<<blocks, 256, 0, stream>>>(eouts, w_eff, b_eff, alpha, B, T, D);
        k_chain<<<B, 256, 2 * T * sizeof(float), stream>>>(
            alpha, nullptr, nullptr, 0,
            elens, ylens, alpha, anorm,
            n_fired, fire_t, fire_a1, fire_a2, T, Lp1);
    }

    {
        int tcpb = (T + 255) / 256;
        int AB = B * tcpb;
        int nLh = (L + 1) / 2;
        if (nLh < 1) nLh = 1;
        int FB = B * nLh;
        k_awfired<<<AB + FB, 256, 0, stream>>>(eouts, anorm,
                                               elens, ylens, n_fired,
                                               fire_t, fire_a1, fire_a2,
                                               aws, fired, T, D, L, Lp1,
                                               AB, tcpb, nLh);
    }
}

// Round 4
// 159.252 us; speedup vs baseline: 1.1896x; 1.1896x over previous
//
#include <hip/hip_runtime.h>
#include <math.h>

#define KHALF 5
#define MAXF 256  // max fire count per batch (Lp1 <= 128 here)

__device__ inline float readlane_f(float v, int lane) {
    return __int_as_float(__builtin_amdgcn_readlane(__float_as_int(v), lane));
}

// K0 "prep": fused weff + aws zero-background.
// Blocks [0, WB): w_eff/b_eff (one wave per output element).
// Blocks [WB, WB+NFILL): grid-stride float4 zero of aws (17 MB at ~full BW;
// lets k_awfired write only the <=2 nonzero entries per column).
__global__ void k_prep(const float* __restrict__ conv_w, const float* __restrict__ conv_b,
                       const float* __restrict__ proj_w, const float* __restrict__ proj_b,
                       float* __restrict__ w_eff, float* __restrict__ b_eff,
                       int KD, int C,
                       float* __restrict__ aws, long long awsN, int WB, int NFILL) {
    if ((int)blockIdx.x >= WB) {
        long long N4 = awsN >> 2;
        long long gid = (long long)(blockIdx.x - WB) * 256 + threadIdx.x;
        float4 z = make_float4(0.f, 0.f, 0.f, 0.f);
        float4* a4 = reinterpret_cast<float4*>(aws);
        long long stride = (long long)NFILL * 256;
        for (long long i = gid; i < N4; i += stride) a4[i] = z;
        int tail = (int)(awsN & 3);
        if (gid < tail) aws[4 * N4 + gid] = 0.f;
        return;
    }
    int gid = blockIdx.x * blockDim.x + threadIdx.x;
    int wave = gid >> 6;
    int lane = gid & 63;
    if (wave > KD) return;
    float s = 0.f;
    if (wave < KD) {
        const float* row = conv_w + (size_t)wave * C;
        for (int c = lane * 4; c < C; c += 256) {
            float4 v = *reinterpret_cast<const float4*>(row + c);
            float4 w = *reinterpret_cast<const float4*>(proj_w + c);
            s += v.x * w.x + v.y * w.y + v.z * w.z + v.w * w.w;
        }
    } else {
        for (int c = lane; c < C; c += 64) s += conv_b[c] * proj_w[c];
    }
#pragma unroll
    for (int off = 32; off > 0; off >>= 1) s += __shfl_down(s, off, 64);
    if (lane == 0) {
        if (wave < KD) w_eff[wave] = s;
        else           b_eff[0] = s + proj_b[0];
    }
}

// K2a: q[u][k] = dot(eouts[u,:], w_eff[k,:]), k=0..10. D==512 specialized.
// (unchanged — near its HBM floor)
__global__ __launch_bounds__(256) void k_qdot(const float* __restrict__ eouts,
                                              const float* __restrict__ w_eff,
                                              float* __restrict__ q, int BT) {
    __shared__ float tile[64 * 68];   // 17408 B
    __shared__ float wls[11 * 68];    //  2992 B
    __shared__ float part[64 * 89];   // 22784 B
    const int u0 = blockIdx.x * 64;
    const int rp = threadIdx.x & 31;
    const int s8 = threadIdx.x >> 5;
    float acc0[11], acc1[11];
#pragma unroll
    for (int k = 0; k < 11; ++k) { acc0[k] = 0.f; acc1[k] = 0.f; }
    for (int c = 0; c < 8; ++c) {
        __syncthreads();
#pragma unroll
        for (int it = 0; it < 4; ++it) {
            int idx = it * 256 + threadIdx.x;
            int r = idx >> 4, j4 = idx & 15;
            float4 v = *reinterpret_cast<const float4*>(
                eouts + (size_t)(u0 + r) * 512 + c * 64 + j4 * 4);
            *reinterpret_cast<float4*>(&tile[r * 68 + j4 * 4]) = v;
        }
        if (threadIdx.x < 176) {
            int k = threadIdx.x >> 4, sl = threadIdx.x & 15;
            float4 wv = *reinterpret_cast<const float4*>(
                w_eff + k * 512 + c * 64 + sl * 4);
            *reinterpret_cast<float4*>(&wls[k * 68 + sl * 4]) = wv;
        }
        __syncthreads();
#pragma unroll
        for (int j4 = 0; j4 < 2; ++j4) {
            const int dl = s8 * 8 + j4 * 4;
            float4 a0 = *reinterpret_cast<const float4*>(&tile[rp * 68 + dl]);
            float4 a1 = *reinterpret_cast<const float4*>(&tile[(rp + 32) * 68 + dl]);
#pragma unroll
            for (int k = 0; k < 11; ++k) {
                float4 wv = *reinterpret_cast<const float4*>(&wls[k * 68 + dl]);
                acc0[k] += a0.x * wv.x + a0.y * wv.y + a0.z * wv.z + a0.w * wv.w;
                acc1[k] += a1.x * wv.x + a1.y * wv.y + a1.z * wv.z + a1.w * wv.w;
            }
        }
    }
    __syncthreads();
#pragma unroll
    for (int k = 0; k < 11; ++k) {
        part[rp * 89 + s8 * 11 + k] = acc0[k];
        part[(rp + 32) * 89 + s8 * 11 + k] = acc1[k];
    }
    __syncthreads();
    if (threadIdx.x < 64) {
        int r = threadIdx.x;
        const float* p = &part[r * 89];
        float o[12];
#pragma unroll
        for (int k = 0; k < 11; ++k) {
            float s0 = (p[0 * 11 + k] + p[1 * 11 + k]) + (p[2 * 11 + k] + p[3 * 11 + k]);
            float s1 = (p[4 * 11 + k] + p[5 * 11 + k]) + (p[6 * 11 + k] + p[7 * 11 + k]);
            o[k] = s0 + s1;
        }
        o[11] = 0.f;
        float4* dst = reinterpret_cast<float4*>(q + (size_t)(u0 + r) * 12);
        dst[0] = make_float4(o[0], o[1], o[2], o[3]);
        dst[1] = make_float4(o[4], o[5], o[6], o[7]);
        dst[2] = make_float4(o[8], o[9], o[10], o[11]);
    }
}

// K2b: alpha[b,t] = sigmoid(sum_k q[t-5+k][k] + bias) + per-block partial sums.
// (reinstated as a separate 128-block kernel — the R3 fusion into the
// 16-block k_chain was the +26us regression)
__global__ __launch_bounds__(256) void k_sigpart(const float* __restrict__ q,
                                                 const float* __restrict__ b_eff,
                                                 float* __restrict__ alpha,
                                                 float* __restrict__ partials,
                                                 int T, int tcb) {
    __shared__ float qs[266 * 12];
    __shared__ float psm[4];
    int bx = blockIdx.x;
    int b = bx / tcb, tc = bx % tcb;
    int t0 = tc * 256;
    const float* qb = q + (size_t)b * T * 12;
    const int base = (t0 - 5) * 12;
    const int lim = T * 12;
    for (int i = threadIdx.x; i < 266 * 12; i += 256) {
        int gi = base + i;
        qs[i] = (gi >= 0 && gi < lim) ? qb[gi] : 0.f;
    }
    __syncthreads();
    int t = t0 + threadIdx.x;
    float sacc = b_eff[0];
#pragma unroll
    for (int k = 0; k < 11; ++k) sacc += qs[(threadIdx.x + k) * 12 + k];
    float al = 1.f / (1.f + expf(-sacc));
    alpha[(size_t)b * T + t] = al;
    float s = al;
    int lane = threadIdx.x & 63;
    int w = threadIdx.x >> 6;
#pragma unroll
    for (int off = 32; off > 0; off >>= 1) s += __shfl_down(s, off, 64);
    if (lane == 0) psm[w] = s;
    __syncthreads();
    if (threadIdx.x == 0) {
        float tot = 0.f;
        for (int i = 0; i < 4; ++i) tot += psm[i];
        partials[bx] = tot;
    }
}

// K2 fallback (generic D): windowed dot, one wave per (b,t), writes alpha.
__global__ void k_alpha(const float* __restrict__ eouts,
                        const float* __restrict__ w_eff,
                        const float* __restrict__ b_eff,
                        float* __restrict__ alpha,
                        int B, int T, int D) {
    const int W = 2 * KHALF + 1;
    int gid = blockIdx.x * blockDim.x + threadIdx.x;
    int wave = gid >> 6;
    int lane = gid & 63;
    if (wave >= B * T) return;
    int b = wave / T;
    int t = wave - b * T;
    int WD = W * D;
    int t0 = t - KHALF;
    float s = 0.f;
    if (t0 >= 0 && t0 + W <= T) {
        const float* base = eouts + ((size_t)b * T + t0) * D;
        for (int j = lane * 4; j < WD; j += 256) {
            float4 v = *reinterpret_cast<const float4*>(base + j);
            float4 w = *reinterpret_cast<const float4*>(w_eff + j);
            s += v.x * w.x + v.y * w.y + v.z * w.z + v.w * w.w;
        }
    } else {
        const float* base = eouts + (size_t)b * T * D;
        for (int j = lane; j < WD; j += 64) {
            int tt = t0 + j / D;
            if (tt >= 0 && tt < T) {
                int d = j - (j / D) * D;
                s += base[(size_t)tt * D + d] * w_eff[j];
            }
        }
    }
#pragma unroll
    for (int off = 32; off > 0; off >>= 1) s += __shfl_down(s, off, 64);
    if (lane == 0) {
        float logit = s + b_eff[0];
        alpha[(size_t)b * T + t] = 1.f / (1.f + expf(-logit));
    }
}

// K3 v8: rowsum (partials) + normalize + fire scan.
// v8 change vs v6 (R2's passing version): the per-fire broadcast LDS reads
// (pf[t0+u], an[t0+u] — ~120cy latency each, serially dependent) are replaced
// by v_readlane from registers: lane l already holds P(t0+l); a(t0+l) is
// loaded to a register at chunk start. u = ctz(ballot) is a uniform scalar,
// so readlane is a few cycles. Values bit-identical to the LDS reads ->
// fire positions bit-identical vs R2.
__global__ void k_chain(const float* __restrict__ alpha_in,
                        int use_part,
                        const float* __restrict__ partials, int npart,
                        const int* __restrict__ elens,
                        const int* __restrict__ ylens,
                        float* __restrict__ anorm,
                        int* __restrict__ n_fired,
                        int* __restrict__ fire_t,
                        float* __restrict__ fire_a1,
                        float* __restrict__ fire_a2,
                        int T, int Lp1) {
    extern __shared__ float an[];   // [0,T): normalized alpha; [T,2T): chunk prefix
    float* pf = an + T;
    __shared__ float sm[16];
    __shared__ float stot;
    int b = blockIdx.x;
    const float* row = alpha_in + (size_t)b * T;
    if ((T & 1023) == 0) {
        const float4* r4 = reinterpret_cast<const float4*>(row);
        float4* a4 = reinterpret_cast<float4*>(an);
        for (int i = threadIdx.x; i < (T >> 2); i += blockDim.x) a4[i] = r4[i];
    } else {
        for (int i = threadIdx.x; i < T; i += blockDim.x) an[i] = row[i];
    }
    __syncthreads();
    if (use_part) {
        if (threadIdx.x < npart && threadIdx.x < 16)
            sm[threadIdx.x] = partials[b * npart + threadIdx.x];
        __syncthreads();
        if (threadIdx.x == 0) {
            float tot = 0.f;
            if (npart <= 16) { for (int i = 0; i < npart; ++i) tot += sm[i]; }
            else { for (int i = 0; i < npart; ++i) tot += partials[b * npart + i]; }
            stot = tot;
        }
    } else {
        float s = 0.f;
        for (int i = threadIdx.x; i < T; i += blockDim.x) s += an[i];
        int lane0 = threadIdx.x & 63;
        int w0 = threadIdx.x >> 6;
#pragma unroll
        for (int off = 32; off > 0; off >>= 1) s += __shfl_down(s, off, 64);
        if (lane0 == 0) sm[w0] = s;
        __syncthreads();
        if (threadIdx.x == 0) {
            float tot = 0.f;
            int nw = blockDim.x >> 6;
            for (int i = 0; i < nw; ++i) tot += sm[i];
            stot = tot;
        }
    }
    __syncthreads();
    float ssum = stot;
    float yl = (float)ylens[b];
    float* __restrict__ anb = anorm + (size_t)b * T;
    for (int i = threadIdx.x; i < T; i += blockDim.x) {
        float v = an[i] / ssum * yl;
        an[i] = v;
        anb[i] = v;
    }
    __syncthreads();
    // per-64-chunk inclusive prefix (same tree order as before)
    {
        int wv = threadIdx.x >> 6, ln = threadIdx.x & 63;
        int nchunks = (T + 63) >> 6;
        for (int c = wv; c < nchunks; c += 4) {
            int t = c * 64 + ln;
            float P = (t < T) ? an[t] : 0.f;
#pragma unroll
            for (int off = 1; off < 64; off <<= 1) {
                float tmp = __shfl_up(P, off, 64);
                if (ln >= off) P += tmp;
            }
            if (t < T) pf[t] = P;
        }
    }
    __syncthreads();
    if (threadIdx.x >= 64) return;
    int lane = threadIdx.x;
    int elen = elens[b];
    if (elen > T) elen = T;
    const int ylen = ylens[b];
    int* __restrict__ ft = fire_t + (size_t)b * Lp1;
    float* __restrict__ fa1 = fire_a1 + (size_t)b * Lp1;
    float* __restrict__ fa2 = fire_a2 + (size_t)b * Lp1;
    float accum = 0.f;
    int n = 0;
    bool done = false;
    for (int t0 = 0; t0 < elen && !done; t0 += 64) {
        int nv = elen - t0;
        if (nv > 64) nv = 64;
        bool inb = (t0 + lane < T);
        float P = inb ? pf[t0 + lane] : 0.f;
        float av = inb ? an[t0 + lane] : 0.f;
        unsigned long long validmask = (nv == 64) ? ~0ull : ((1ull << nv) - 1ull);
        float base = accum;
        int start = 0;
        while (true) {
            bool cond = (base + P >= 0.9f);
            unsigned long long bal = __ballot(cond) & validmask;
            if (start > 0) bal &= (~0ull) << start;
            if (bal == 0) break;
            int u = __builtin_ctzll(bal);
            float Pu = readlane_f(P, u);    // register, uniform lane idx
            float au = readlane_f(av, u);   // register, uniform lane idx
            float accum_f = base + Pu;
            float ak1 = 1.f - accum_f;
            float ak2 = au - ak1;
            if (lane == 0) { ft[n] = t0 + u; fa1[n] = ak1; fa2[n] = ak2; }
            ++n;
            if (n >= ylen) { done = true; break; }
            base = ak2 - Pu;
            start = u + 1;
            if (start >= nv) break;
        }
        if (!done) accum = base + readlane_f(P, nv - 1);
    }
    if (lane == 0) n_fired[b] = n;
}

// K4: aws sparse writer (background pre-zeroed by k_prep) + fired (float4,
// 4-deep t-unroll). Unchanged from R3.
__global__ void k_awfired(const float* __restrict__ eouts,
                          const float* __restrict__ anorm,
                          const int* __restrict__ elens,
                          const int* __restrict__ ylens,
                          const int* __restrict__ n_fired,
                          const int* __restrict__ fire_t,
                          const float* __restrict__ fire_a1,
                          const float* __restrict__ fire_a2,
                          float* __restrict__ aws,
                          float* __restrict__ fired,
                          int T, int D, int L, int Lp1,
                          int AB, int tcpb, int nLh) {
    if ((int)blockIdx.x < AB) {
        __shared__ int fts[MAXF];
        __shared__ float a1s[MAXF];
        __shared__ float a2s[MAXF];
        int b = blockIdx.x / tcpb;
        int tc = blockIdx.x % tcpb;
        int nf = n_fired[b];
        for (int i = threadIdx.x; i < nf; i += blockDim.x) {
            fts[i] = fire_t[(size_t)b * Lp1 + i];
            a1s[i] = fire_a1[(size_t)b * Lp1 + i];
            a2s[i] = fire_a2[(size_t)b * Lp1 + i];
        }
        __syncthreads();
        int t = tc * 256 + threadIdx.x;
        if (t >= T) return;
        int elen = elens[b];
        if (elen > T) elen = T;
        int ylen = ylens[b];
        if (t >= elen) return;                 // background zero (pre-zeroed)
        int lo = 0, hi = nf;
        while (lo < hi) {
            int mid = (lo + hi) >> 1;
            if (fts[mid] < t) lo = mid + 1; else hi = mid;
        }
        int rowi = lo;
        bool isfire = (rowi < nf && fts[rowi] == t);
        float* col = aws + (size_t)b * Lp1 * T + t;
        if (isfire) {
            col[(size_t)rowi * T] = a1s[rowi];
            col[(size_t)(rowi + 1) * T] = a2s[rowi];
        } else if (rowi < ylen) {
            col[(size_t)rowi * T] = anorm[(size_t)b * T + t];
        }
    } else {
        int idx = blockIdx.x - AB;
        int b = idx / nLh;
        int j = idx % nLh;
        int half = threadIdx.x >> 7;
        int dl = threadIdx.x & 127;
        int n = 2 * j + half;
        if (n >= L) return;
        int nf = n_fired[b];
        if ((D & 3) == 0) {
            int D4 = D >> 2;
            float4* dst = reinterpret_cast<float4*>(fired + ((size_t)b * L + n) * D);
            if (n >= nf) {
                for (int d4 = dl; d4 < D4; d4 += 128)
                    dst[d4] = make_float4(0.f, 0.f, 0.f, 0.f);
                return;
            }
            int t0 = (n == 0) ? 0 : fire_t[(size_t)b * Lp1 + n - 1];
            int t1 = fire_t[(size_t)b * Lp1 + n];
            float ak1 = fire_a1[(size_t)b * Lp1 + n];
            float ak2p = (n > 0) ? fire_a2[(size_t)b * Lp1 + n - 1] : 0.f;
            const float* an_g = anorm + (size_t)b * T;
            const float4* ebase = reinterpret_cast<const float4*>(
                eouts + ((size_t)b * T + t0) * D);
            for (int d4 = dl; d4 < D4; d4 += 128) {
                const float4* e = ebase + d4;
                float4 accv;
                if (t1 == t0) {
                    float4 v = e[0];
                    accv.x = ak1 * v.x; accv.y = ak1 * v.y;
                    accv.z = ak1 * v.z; accv.w = ak1 * v.w;
                } else {
                    float w0 = (n > 0) ? ak2p : an_g[t0];
                    float4 v = e[0];
                    accv.x = w0 * v.x; accv.y = w0 * v.y;
                    accv.z = w0 * v.z; accv.w = w0 * v.w;
                    float4 a0 = make_float4(0.f, 0.f, 0.f, 0.f);
                    float4 a1 = a0, a2 = a0, a3 = a0;
                    int t = t0 + 1;
                    const float4* ee = e + D4;
                    for (; t + 3 < t1; t += 4, ee += 4 * (size_t)D4) {
                        float wa = an_g[t], wb = an_g[t + 1];
                        float wc = an_g[t + 2], wd = an_g[t + 3];
                        float4 va = ee[0], vb = ee[D4], vc = ee[2 * (size_t)D4], vd = ee[3 * (size_t)D4];
                        a0.x += wa * va.x; a0.y += wa * va.y; a0.z += wa * va.z; a0.w += wa * va.w;
                        a1.x += wb * vb.x; a1.y += wb * vb.y; a1.z += wb * vb.z; a1.w += wb * vb.w;
                        a2.x += wc * vc.x; a2.y += wc * vc.y; a2.z += wc * vc.z; a2.w += wc * vc.w;
                        a3.x += wd * vd.x; a3.y += wd * vd.y; a3.z += wd * vd.z; a3.w += wd * vd.w;
                    }
                    for (; t < t1; ++t, ee += D4) {
                        float wa = an_g[t];
                        float4 va = ee[0];
                        a0.x += wa * va.x; a0.y += wa * va.y; a0.z += wa * va.z; a0.w += wa * va.w;
                    }
                    accv.x += ((a0.x + a1.x) + (a2.x + a3.x));
                    accv.y += ((a0.y + a1.y) + (a2.y + a3.y));
                    accv.z += ((a0.z + a1.z) + (a2.z + a3.z));
                    accv.w += ((a0.w + a1.w) + (a2.w + a3.w));
                    float4 vl = ee[0];   // row t1
                    accv.x += ak1 * vl.x; accv.y += ak1 * vl.y;
                    accv.z += ak1 * vl.z; accv.w += ak1 * vl.w;
                }
                dst[d4] = accv;
            }
        } else {
            float* dst = fired + ((size_t)b * L + n) * D;
            if (n >= nf) {
                for (int d = dl; d < D; d += 128) dst[d] = 0.f;
                return;
            }
            int t0 = (n == 0) ? 0 : fire_t[(size_t)b * Lp1 + n - 1];
            int t1 = fire_t[(size_t)b * Lp1 + n];
            float ak1 = fire_a1[(size_t)b * Lp1 + n];
            float ak2p = (n > 0) ? fire_a2[(size_t)b * Lp1 + n - 1] : 0.f;
            const float* an_g = anorm + (size_t)b * T;
            for (int d = dl; d < D; d += 128) {
                const float* e = eouts + ((size_t)b * T + t0) * D + d;
                float accv;
                if (t1 == t0) {
                    accv = ak1 * e[0];
                } else {
                    float w0 = (n > 0) ? ak2p : an_g[t0];
                    accv = w0 * e[0];
                    float a0 = 0.f, a1 = 0.f, a2 = 0.f, a3 = 0.f;
                    int t = t0 + 1;
                    const float* ee = e + D;
                    for (; t + 3 < t1; t += 4, ee += 4 * (size_t)D) {
                        a0 += an_g[t]     * ee[0];
                        a1 += an_g[t + 1] * ee[D];
                        a2 += an_g[t + 2] * ee[2 * (size_t)D];
                        a3 += an_g[t + 3] * ee[3 * (size_t)D];
                    }
                    for (; t < t1; ++t, ee += D) a0 += an_g[t] * ee[0];
                    accv += ((a0 + a1) + (a2 + a3));
                    accv += ak1 * ee[0];
                }
                dst[d] = accv;
            }
        }
    }
}

extern "C" void kernel_launch(void* const* d_in, const int* in_sizes, int n_in,
                              void* d_out, int out_size, void* d_ws, size_t ws_size,
                              hipStream_t stream) {
    const float* eouts  = (const float*)d_in[0];
    const float* conv_w = (const float*)d_in[1];
    const float* conv_b = (const float*)d_in[2];
    const float* proj_w = (const float*)d_in[3];
    const float* proj_b = (const float*)d_in[4];
    const int*   elens  = (const int*)d_in[5];
    const int*   ylens  = (const int*)d_in[6];

    const int B = in_sizes[5];
    const int C = in_sizes[2];
    const int W = 2 * KHALF + 1;
    const int D = in_sizes[1] / (W * C);
    const int T = in_sizes[0] / (B * D);
    const int L = (out_size - 2 * B * T) / (B * (D + T));
    const int Lp1 = L + 1;
    const int BT = B * T;
    const int tcb = (T + 255) / 256;

    float* out   = (float*)d_out;
    float* fired = out;                      // [B, L, D]
    float* alpha = out + (size_t)B * L * D;  // [B, T]
    float* aws   = alpha + (size_t)B * T;    // [B, 1, Lp1, T]

    char*  ws        = (char*)d_ws;
    float* w_eff     = (float*)ws;                              // W*D floats
    float* b_eff     = (float*)(ws + (size_t)W * D * 4);        // 1 float (+pad)
    int*   n_fired   = (int*)(b_eff + 16);                      // B ints
    int*   fire_t    = n_fired + B + 16;                        // B*Lp1 ints
    float* fire_a1   = (float*)(fire_t + (size_t)B * Lp1 + 16); // B*Lp1 floats
    float* fire_a2   = fire_a1 + (size_t)B * Lp1 + 16;          // B*Lp1 floats
    float* anorm     = fire_a2 + (size_t)B * Lp1 + 16;          // B*T floats
    float* qbuf      = anorm + (size_t)B * T + 16;              // BT*12 floats
    float* partials  = qbuf + (size_t)BT * 12 + 16;             // B*tcb floats
    size_t ws_need   = (size_t)((char*)(partials + (size_t)B * tcb + 16) - ws);

    const int KD = W * D;
    {
        long long wthreads = (long long)(KD + 1) * 64;
        int WB = (int)((wthreads + 255) / 256);
        int NFILL = 2048;
        long long awsN = (long long)B * Lp1 * T;
        k_prep<<<WB + NFILL, 256, 0, stream>>>(conv_w, conv_b, proj_w, proj_b,
                                               w_eff, b_eff, KD, C,
                                               aws, awsN, WB, NFILL);
    }

    const bool fast = (ws_size >= ws_need) && (D == 512) && (C == 512) &&
                      (BT % 64 == 0) && (T % 256 == 0) && (T <= 16384) &&
                      (Lp1 <= MAXF);
    if (fast) {
        k_qdot<<<BT / 64, 256, 0, stream>>>(eouts, w_eff, qbuf, BT);
        k_sigpart<<<B * tcb, 256, 0, stream>>>(qbuf, b_eff, alpha, partials, T, tcb);
    } else {
        long long threads = (long long)BT * 64;
        int blocks = (int)((threads + 255) / 256);
        k_alpha<<<blocks, 256, 0, stream>>>(eouts, w_eff, b_eff, alpha, B, T, D);
    }

    // dynamic LDS: an[T] + pf[T]
    k_chain<<<B, 256, 2 * T * sizeof(float), stream>>>(
        alpha, fast ? 1 : 0, partials, tcb,
        elens, ylens, anorm,
        n_fired, fire_t, fire_a1, fire_a2, T, Lp1);

    {
        int tcpb = (T + 255) / 256;
        int AB = B * tcpb;
        int nLh = (L + 1) / 2;
        if (nLh < 1) nLh = 1;
        int FB = B * nLh;
        k_awfired<<<AB + FB, 256, 0, stream>>>(eouts, anorm,
                                               elens, ylens, n_fired,
                                               fire_t, fire_a1, fire_a2,
                                               aws, fired, T, D, L, Lp1,
                                               AB, tcpb, nLh);
    }
}